// Round 9
// baseline (335.008 us; speedup 1.0000x reference)
//
#include <hip/hip_runtime.h>

#define W_  512
#define H_  512
#define HW  (512 * 512)   // 2^18
#define P_  20
#define B_  8
#define TL_ 29
#define IL_ 9

#define NT  256
#define NBLK 4096               // 512 blocks/batch x 8 batches
#define HALF (HW / 2)           // 131072 px per j-slice

// One advect step. R9: 2 px/thread, TOT-strided (lanes remain stride-1 over
// pixels — R3 proved consecutive-px/thread kills gather coalescing; striding
// keeps it). Halves block count (4096) and doubles per-wave MLP (6 stream
// loads + 10 gathers + 8 stores in flight) to push short kernels closer to
// steady-state BW. Batch->XCD affinity kept: b = bid & 7.
// Carry for p>0 reads evo_result[p-1]*128 — exact (pow2 commutes with lerp).
__global__ __launch_bounds__(NT) void step_kernel(
    const float* __restrict__ prev_base,   // carry source, per-batch stride prev_stride
    long prev_stride,
    float prev_scale,                      // 1.0 frames / 128.0 evo_result readback
    const float* __restrict__ motion,      // (B, 2P, H, W)
    const float* __restrict__ intensity,   // (B, P, H, W)
    float* __restrict__ evo_result,        // (B, P, H, W)
    float* __restrict__ evo_motion,        // (B, P, H, W)
    float* __restrict__ motion_out,        // (B, 2P, H, W)
    int p)
{
    const int b    = blockIdx.x & 7;                          // batch -> XCD
    const int base = ((blockIdx.x >> 3) << 8) + threadIdx.x;  // 0..131071

    const float* prev = prev_base + (long)b * prev_stride;
    const long moP = ((long)b * (2 * P_) + 2 * p) * HW;       // flow-x plane base
    const long ioP = ((long)b * P_ + p) * HW;                 // intensity/out base

    #pragma unroll
    for (int j = 0; j < 2; ++j) {
        const int rem = base + j * HALF;    // lanes stride-1 over pixels
        const int y   = rem >> 9;
        const int x   = rem & (W_ - 1);

        const long mo0 = moP + rem;
        const long io  = ioP + rem;

        const float f0 = __builtin_nontemporal_load(motion + mo0);
        const float f1 = __builtin_nontemporal_load(motion + mo0 + HW);
        const float iv = __builtin_nontemporal_load(intensity + io);

        // motion_ output = pure copy, from registers
        __builtin_nontemporal_store(f0, motion_out + mo0);
        __builtin_nontemporal_store(f1, motion_out + mo0 + HW);

        const float cx = fminf(fmaxf((float)x + f0, 0.0f), 511.0f);
        const float cy = fminf(fmaxf((float)y + f1, 0.0f), 511.0f);

        const float x0f = floorf(cx), y0f = floorf(cy);
        const float wx = cx - x0f, wy = cy - y0f;
        const int x0 = (int)x0f, y0 = (int)y0f;
        const int x1 = min(x0 + 1, W_ - 1), y1 = min(y0 + 1, H_ - 1);

        const float* r0 = prev + y0 * W_;
        const float* r1 = prev + y1 * W_;
        const float v00 = r0[x0], v01 = r0[x1];
        const float v10 = r1[x0], v11 = r1[x1];
        const float bil = prev_scale * ((1.0f - wy) * ((1.0f - wx) * v00 + wx * v01)
                                              + wy  * ((1.0f - wx) * v10 + wx * v11));

        const int xi = (int)rintf(cx);   // half-to-even == jnp.round
        const int yi = (int)rintf(cy);
        const float res = (prev_scale * prev[yi * W_ + xi] + iv) * 0.0078125f; // /128

        evo_result[io] = res;                              // cached (re-read next step)
        __builtin_nontemporal_store(bil, evo_motion + io); // write-only
    }
}

extern "C" void kernel_launch(void* const* d_in, const int* in_sizes, int n_in,
                              void* d_out, int out_size, void* d_ws, size_t ws_size,
                              hipStream_t stream)
{
    const float* frames    = (const float*)d_in[0];  // (B, TL, H, W, 1)
    const float* motion    = (const float*)d_in[1];  // (B, 2P, H, W)
    const float* intensity = (const float*)d_in[2];  // (B, P, H, W)

    float* out        = (float*)d_out;
    float* evo_result = out;                          // B*P*HW
    float* evo_motion = out + (long)B_ * P_ * HW;     // B*P*HW
    float* motion_out = out + 2L * B_ * P_ * HW;      // B*2P*HW

    // step 0: carry = frames[:, IL-1, :, :, 0]
    step_kernel<<<NBLK, NT, 0, stream>>>(
        frames + (long)(IL_ - 1) * HW, (long)TL_ * HW, 1.0f,
        motion, intensity, evo_result, evo_motion, motion_out, 0);

    // steps 1..P-1: carry = evo_result[:, p-1] * 128 (exact)
    for (int p = 1; p < P_; ++p) {
        step_kernel<<<NBLK, NT, 0, stream>>>(
            evo_result + (long)(p - 1) * HW, (long)P_ * HW, 128.0f,
            motion, intensity, evo_result, evo_motion, motion_out, p);
    }
}